// Round 3
// baseline (587.627 us; speedup 1.0000x reference)
//
#include <hip/hip_runtime.h>
#include <math.h>

#define NF 64  // feature width of every GCN layer output

// ================= CSR build =================

__global__ void zero_int_kernel(int* __restrict__ p, int n) {
    int i = blockIdx.x * blockDim.x + threadIdx.x;
    if (i < n) p[i] = 0;
}

__global__ void hist_kernel(const int* __restrict__ dst, int* __restrict__ counts, int e) {
    int i = blockIdx.x * blockDim.x + threadIdx.x;
    if (i < e) atomicAdd(&counts[dst[i]], 1);
}

__global__ void dis_kernel(const int* __restrict__ counts, float* __restrict__ dis, int n) {
    int i = blockIdx.x * blockDim.x + threadIdx.x;
    if (i < n) dis[i] = rsqrtf((float)counts[i] + 1.0f);  // +1 = self-loop
}

// per-1024-block exclusive scan of counts -> row_ptr, block totals -> bsums
__global__ void block_scan_kernel(const int* __restrict__ counts, int* __restrict__ row_ptr,
                                  int* __restrict__ bsums, int n) {
    __shared__ int s[1024];
    int t = threadIdx.x;
    int g = blockIdx.x * 1024 + t;
    int v = (g < n) ? counts[g] : 0;
    s[t] = v;
    __syncthreads();
#pragma unroll
    for (int off = 1; off < 1024; off <<= 1) {
        int add = (t >= off) ? s[t - off] : 0;
        __syncthreads();
        s[t] += add;
        __syncthreads();
    }
    if (g < n) row_ptr[g] = s[t] - v;  // exclusive
    if (t == 1023) bsums[blockIdx.x] = s[t];
}

__global__ void scan_bsums_kernel(int* __restrict__ bsums, int nb) {
    int t = threadIdx.x;  // blockDim = 64
    int v = (t < nb) ? bsums[t] : 0;
    int orig = v;
#pragma unroll
    for (int off = 1; off < 64; off <<= 1) {
        int u = __shfl_up(v, off, 64);
        if (t >= off) v += u;
    }
    if (t < nb) bsums[t] = v - orig;  // exclusive
}

__global__ void add_offsets_kernel(int* __restrict__ row_ptr, const int* __restrict__ bsums,
                                   int* __restrict__ cursor, int n, int e) {
    int g = blockIdx.x * blockDim.x + threadIdx.x;
    if (g < n) {
        int r = row_ptr[g] + bsums[g >> 10];
        row_ptr[g] = r;
        cursor[g] = r;
    }
    if (g == 0) row_ptr[n] = e;
}

__global__ void fill_kernel(const int* __restrict__ ei, int* __restrict__ cursor,
                            int* __restrict__ col, int e) {
    int i = blockIdx.x * blockDim.x + threadIdx.x;
    if (i < e) {
        int d = ei[e + i];  // dst
        int j = atomicAdd(&cursor[d], 1);
        col[j] = ei[i];  // src
    }
}

// ================= h' = (X @ W) * dis[row] — register-tiled SGEMM =================
// Block: 64 nodes x 64 feats, 256 threads, each thread 4x4 outputs.
// K staged in 64-chunks: Xs = X^T tile [k][node] (pad 68), Ws = W tile [k][feat].

template <int K>
__global__ __launch_bounds__(256) void gemm_tile_kernel(const float* __restrict__ X,
                                                        const float* __restrict__ W,
                                                        const float* __restrict__ dis,
                                                        float* __restrict__ h, int n) {
    __shared__ float Xs[64][68];
    __shared__ float Ws[64][64];
    int t = threadIdx.x;
    int tx = t & 15;  // feat quad index
    int ty = t >> 4;  // node quad index
    int node0 = blockIdx.x * 64;

    float acc[4][4] = {{0.f}};

    for (int kb = 0; kb < K; kb += 64) {
        // ---- stage X^T: thread (i = t>>2, q = t&3) loads 16 k-values of node row i
        int i = t >> 2, q = t & 3;
        int nodei = node0 + i;
        if (nodei < n) {
            const float* xr = X + (size_t)nodei * K + kb + q * 16;
#pragma unroll
            for (int f4 = 0; f4 < 4; ++f4) {
                float4 v = *reinterpret_cast<const float4*>(xr + f4 * 4);
                Xs[q * 16 + f4 * 4 + 0][i] = v.x;
                Xs[q * 16 + f4 * 4 + 1][i] = v.y;
                Xs[q * 16 + f4 * 4 + 2][i] = v.z;
                Xs[q * 16 + f4 * 4 + 3][i] = v.w;
            }
        } else {
#pragma unroll
            for (int kk = 0; kk < 16; ++kk) Xs[q * 16 + kk][i] = 0.0f;
        }
        // ---- stage W: 64x64 floats, linear copy, 16 floats/thread
        {
            const float* wr = W + (size_t)kb * 64 + t * 16;
            float* wsf = &Ws[0][0] + t * 16;
#pragma unroll
            for (int f4 = 0; f4 < 4; ++f4)
                *reinterpret_cast<float4*>(wsf + f4 * 4) =
                    *reinterpret_cast<const float4*>(wr + f4 * 4);
        }
        __syncthreads();
#pragma unroll
        for (int k = 0; k < 64; ++k) {
            float4 xv = *reinterpret_cast<const float4*>(&Xs[k][ty * 4]);
            float4 wv = *reinterpret_cast<const float4*>(&Ws[k][tx * 4]);
            float xa[4] = {xv.x, xv.y, xv.z, xv.w};
            float wa[4] = {wv.x, wv.y, wv.z, wv.w};
#pragma unroll
            for (int m = 0; m < 4; ++m)
#pragma unroll
                for (int f = 0; f < 4; ++f) acc[m][f] += xa[m] * wa[f];
        }
        __syncthreads();
    }

#pragma unroll
    for (int m = 0; m < 4; ++m) {
        int node = node0 + ty * 4 + m;
        if (node < n) {
            float d = dis[node];
            float4 o = make_float4(acc[m][0] * d, acc[m][1] * d, acc[m][2] * d, acc[m][3] * d);
            *reinterpret_cast<float4*>(&h[(size_t)node * NF + tx * 4]) = o;
        }
    }
}

// ================= pull aggregation (fused finalize) =================
// out[v] = relu?( (h'[v] + sum_{s in N(v)} h'[s]) * dis[v] + b )
// One wave per node, lane = feature; 8-deep batched gather.

__global__ void pull_agg_kernel(const int* __restrict__ row_ptr, const int* __restrict__ col,
                                const float* __restrict__ h, const float* __restrict__ dis,
                                const float* __restrict__ b, float* __restrict__ out, int n,
                                int do_relu) {
    int t = threadIdx.x;
    int node = blockIdx.x * 4 + (t >> 6);
    int lane = t & 63;
    if (node >= n) return;

    int beg = row_ptr[node];
    int end = row_ptr[node + 1];
    float v = h[(size_t)node * NF + lane];  // self-loop

    int j = beg;
    for (; j + 8 <= end; j += 8) {
        int s[8];
#pragma unroll
        for (int q = 0; q < 8; ++q) s[q] = col[j + q];
        float a[8];
#pragma unroll
        for (int q = 0; q < 8; ++q) a[q] = h[(size_t)s[q] * NF + lane];
        float s0 = (a[0] + a[1]) + (a[2] + a[3]);
        float s1 = (a[4] + a[5]) + (a[6] + a[7]);
        v += s0 + s1;
    }
    for (; j < end; ++j) v += h[(size_t)col[j] * NF + lane];

    float r = v * dis[node] + b[lane];
    if (do_relu) r = fmaxf(r, 0.0f);
    out[(size_t)node * NF + lane] = r;
}

// ================= head =================

__global__ void head_kernel(const float* __restrict__ x1, const float* __restrict__ x2,
                            const float* __restrict__ x3, const float* __restrict__ Wl,
                            const float* __restrict__ bl, float* __restrict__ out, int n) {
    __shared__ float Ws[8 * 192];  // Ws[c*192 + j] = Wl[j*8 + c]
    __shared__ float bs[8];
    int t = threadIdx.x;
    for (int idx = t; idx < 8 * 192; idx += 256) {
        int c = idx / 192, j = idx % 192;
        Ws[idx] = Wl[j * 8 + c];
    }
    if (t < 8) bs[t] = bl[t];
    __syncthreads();

    int node = blockIdx.x * 4 + (t >> 6);
    int lane = t & 63;
    if (node >= n) return;

    const float* rows[3] = {x1 + (size_t)node * NF, x2 + (size_t)node * NF,
                            x3 + (size_t)node * NF};
    float acc[8];
#pragma unroll
    for (int c = 0; c < 8; ++c) acc[c] = 0.0f;
#pragma unroll
    for (int p = 0; p < 3; ++p) {
        float v = rows[p][lane];
#pragma unroll
        for (int c = 0; c < 8; ++c) acc[c] += v * Ws[c * 192 + p * 64 + lane];
    }
#pragma unroll
    for (int off = 32; off >= 1; off >>= 1) {
#pragma unroll
        for (int c = 0; c < 8; ++c) acc[c] += __shfl_xor(acc[c], off, 64);
    }
    if (lane < 8) {
        float lg[8];
        float m = -INFINITY;
#pragma unroll
        for (int c = 0; c < 8; ++c) {
            lg[c] = acc[c] + bs[c];
            m = fmaxf(m, lg[c]);
        }
        float s = 0.0f;
#pragma unroll
        for (int c = 0; c < 8; ++c) s += expf(lg[c] - m);
        float lse = m + logf(s);
        out[(size_t)node * 8 + lane] = lg[lane] - lse;
    }
}

// ================= launch =================

extern "C" void kernel_launch(void* const* d_in, const int* in_sizes, int n_in,
                              void* d_out, int out_size, void* d_ws, size_t ws_size,
                              hipStream_t stream) {
    const float* x = (const float*)d_in[0];
    const int* ei = (const int*)d_in[1];  // [2,E]: [0..E)=src, [E..2E)=dst
    const float* W1 = (const float*)d_in[2];
    const float* b1 = (const float*)d_in[3];
    const float* W2 = (const float*)d_in[4];
    const float* b2 = (const float*)d_in[5];
    const float* W3 = (const float*)d_in[6];
    const float* b3 = (const float*)d_in[7];
    const float* Wl = (const float*)d_in[8];
    const float* bl = (const float*)d_in[9];
    float* out = (float*)d_out;

    const int n = in_sizes[0] / 128;  // 50000
    const int e = in_sizes[1] / 2;    // 800000

    // ws layout: dis[n] f32 | row_ptr[n+1] | cursor[n] | bsums[64] | col[e] |
    //            tmp[n*64] f32 | x1 | x2 | x3 (n*64 f32 each)
    float* dis = (float*)d_ws;
    int* row_ptr = (int*)(dis + n);
    int* cursor = row_ptr + (n + 1);
    int* bsums = cursor + n;
    int* col = bsums + 64;
    float* tmp = (float*)(col + e);
    float* x1 = tmp + (size_t)n * NF;
    float* x2 = x1 + (size_t)n * NF;
    float* x3 = x2 + (size_t)n * NF;

    const int B = 256;
    dim3 blk(B);
    dim3 gn((n + B - 1) / B);
    dim3 ge((e + B - 1) / B);
    const int nb = (n + 1023) / 1024;  // scan blocks (49)

    // ---- CSR build (counts live in `cursor`) ----
    zero_int_kernel<<<gn, blk, 0, stream>>>(cursor, n);
    hist_kernel<<<ge, blk, 0, stream>>>(ei + e, cursor, e);
    dis_kernel<<<gn, blk, 0, stream>>>(cursor, dis, n);
    block_scan_kernel<<<dim3(nb), dim3(1024), 0, stream>>>(cursor, row_ptr, bsums, n);
    scan_bsums_kernel<<<dim3(1), dim3(64), 0, stream>>>(bsums, nb);
    add_offsets_kernel<<<gn, blk, 0, stream>>>(row_ptr, bsums, cursor, n, e);
    fill_kernel<<<ge, blk, 0, stream>>>(ei, cursor, col, e);

    dim3 ggemm((n + 63) / 64);  // 64-node tiles
    dim3 gwave((n + 3) / 4);    // wave-per-node kernels

    // ---- layer 1 (K=128, ReLU) ----
    gemm_tile_kernel<128><<<ggemm, blk, 0, stream>>>(x, W1, dis, tmp, n);
    pull_agg_kernel<<<gwave, blk, 0, stream>>>(row_ptr, col, tmp, dis, b1, x1, n, 1);

    // ---- layer 2 (K=64, ReLU) ----
    gemm_tile_kernel<64><<<ggemm, blk, 0, stream>>>(x1, W2, dis, tmp, n);
    pull_agg_kernel<<<gwave, blk, 0, stream>>>(row_ptr, col, tmp, dis, b2, x2, n, 1);

    // ---- layer 3 (K=64, no ReLU) ----
    gemm_tile_kernel<64><<<ggemm, blk, 0, stream>>>(x2, W3, dis, tmp, n);
    pull_agg_kernel<<<gwave, blk, 0, stream>>>(row_ptr, col, tmp, dis, b3, x3, n, 0);

    // ---- head ----
    head_kernel<<<gwave, blk, 0, stream>>>(x1, x2, x3, Wl, bl, out, n);
}

// Round 4
// 333.432 us; speedup vs baseline: 1.7624x; 1.7624x over previous
//
#include <hip/hip_runtime.h>
#include <math.h>

#define NF 64  // feature width of every GCN layer output

// ================= CSR build =================

__global__ void zero_int_kernel(int* __restrict__ p, int n) {
    int i = blockIdx.x * blockDim.x + threadIdx.x;
    if (i < n) p[i] = 0;
}

__global__ void hist_kernel(const int* __restrict__ dst, int* __restrict__ counts, int e) {
    int i = blockIdx.x * blockDim.x + threadIdx.x;
    if (i < e) atomicAdd(&counts[dst[i]], 1);
}

__global__ void dis_kernel(const int* __restrict__ counts, float* __restrict__ dis, int n) {
    int i = blockIdx.x * blockDim.x + threadIdx.x;
    if (i < n) dis[i] = rsqrtf((float)counts[i] + 1.0f);  // +1 = self-loop
}

// per-1024-block exclusive scan of counts -> row_ptr, block totals -> bsums
__global__ void block_scan_kernel(const int* __restrict__ counts, int* __restrict__ row_ptr,
                                  int* __restrict__ bsums, int n) {
    __shared__ int s[1024];
    int t = threadIdx.x;
    int g = blockIdx.x * 1024 + t;
    int v = (g < n) ? counts[g] : 0;
    s[t] = v;
    __syncthreads();
#pragma unroll
    for (int off = 1; off < 1024; off <<= 1) {
        int add = (t >= off) ? s[t - off] : 0;
        __syncthreads();
        s[t] += add;
        __syncthreads();
    }
    if (g < n) row_ptr[g] = s[t] - v;  // exclusive
    if (t == 1023) bsums[blockIdx.x] = s[t];
}

__global__ void scan_bsums_kernel(int* __restrict__ bsums, int nb) {
    int t = threadIdx.x;  // blockDim = 64
    int v = (t < nb) ? bsums[t] : 0;
    int orig = v;
#pragma unroll
    for (int off = 1; off < 64; off <<= 1) {
        int u = __shfl_up(v, off, 64);
        if (t >= off) v += u;
    }
    if (t < nb) bsums[t] = v - orig;  // exclusive
}

__global__ void add_offsets_kernel(int* __restrict__ row_ptr, const int* __restrict__ bsums,
                                   int* __restrict__ cursor, int n, int e) {
    int g = blockIdx.x * blockDim.x + threadIdx.x;
    if (g < n) {
        int r = row_ptr[g] + bsums[g >> 10];
        row_ptr[g] = r;
        cursor[g] = r;
    }
    if (g == 0) row_ptr[n] = e;
}

__global__ void fill_kernel(const int* __restrict__ ei, int* __restrict__ cursor,
                            int* __restrict__ col, int e) {
    int i = blockIdx.x * blockDim.x + threadIdx.x;
    if (i < e) {
        int d = ei[e + i];  // dst
        int j = atomicAdd(&cursor[d], 1);
        col[j] = ei[i];  // src
    }
}

// ================= h' = (X @ W) * dis[row] — register-tiled SGEMM =================
// Block: 64 nodes x 64 feats, 256 threads, each thread 4x4 outputs.
// K staged in 64-chunks: Xs = X^T tile [k][node] (pad 68), Ws = W tile [k][feat].
// Inner k-loop unroll CAPPED at 8: full unroll (r3) hoisted ~128 ds_read results,
// VGPR=256 + scratch spill (188MB fetch / 205MB write of spill traffic).

template <int K>
__global__ __launch_bounds__(256) void gemm_tile_kernel(const float* __restrict__ X,
                                                        const float* __restrict__ W,
                                                        const float* __restrict__ dis,
                                                        float* __restrict__ h, int n) {
    __shared__ float Xs[64][68];
    __shared__ float Ws[64][64];
    int t = threadIdx.x;
    int tx = t & 15;  // feat quad index
    int ty = t >> 4;  // node quad index
    int node0 = blockIdx.x * 64;

    float acc[4][4] = {{0.f}};

    for (int kb = 0; kb < K; kb += 64) {
        // ---- stage X^T: thread (i = t>>2, q = t&3) loads 16 k-values of node row i
        int i = t >> 2, q = t & 3;
        int nodei = node0 + i;
        if (nodei < n) {
            const float* xr = X + (size_t)nodei * K + kb + q * 16;
#pragma unroll
            for (int f4 = 0; f4 < 4; ++f4) {
                float4 v = *reinterpret_cast<const float4*>(xr + f4 * 4);
                Xs[q * 16 + f4 * 4 + 0][i] = v.x;
                Xs[q * 16 + f4 * 4 + 1][i] = v.y;
                Xs[q * 16 + f4 * 4 + 2][i] = v.z;
                Xs[q * 16 + f4 * 4 + 3][i] = v.w;
            }
        } else {
#pragma unroll
            for (int kk = 0; kk < 16; ++kk) Xs[q * 16 + kk][i] = 0.0f;
        }
        // ---- stage W: 64x64 floats, linear copy, 16 floats/thread
        {
            const float* wr = W + (size_t)kb * 64 + t * 16;
            float* wsf = &Ws[0][0] + t * 16;
#pragma unroll
            for (int f4 = 0; f4 < 4; ++f4)
                *reinterpret_cast<float4*>(wsf + f4 * 4) =
                    *reinterpret_cast<const float4*>(wr + f4 * 4);
        }
        __syncthreads();
#pragma unroll 8
        for (int k = 0; k < 64; ++k) {
            float4 xv = *reinterpret_cast<const float4*>(&Xs[k][ty * 4]);
            float4 wv = *reinterpret_cast<const float4*>(&Ws[k][tx * 4]);
            float xa[4] = {xv.x, xv.y, xv.z, xv.w};
            float wa[4] = {wv.x, wv.y, wv.z, wv.w};
#pragma unroll
            for (int m = 0; m < 4; ++m)
#pragma unroll
                for (int f = 0; f < 4; ++f) acc[m][f] += xa[m] * wa[f];
        }
        __syncthreads();
    }

#pragma unroll
    for (int m = 0; m < 4; ++m) {
        int node = node0 + ty * 4 + m;
        if (node < n) {
            float d = dis[node];
            float4 o = make_float4(acc[m][0] * d, acc[m][1] * d, acc[m][2] * d, acc[m][3] * d);
            *reinterpret_cast<float4*>(&h[(size_t)node * NF + tx * 4]) = o;
        }
    }
}

// ================= pull aggregation (fused finalize) =================
// out[v] = relu?( (h'[v] + sum_{s in N(v)} h'[s]) * dis[v] + b )
// One wave per node, lane = feature; 8-deep batched gather.

__global__ void pull_agg_kernel(const int* __restrict__ row_ptr, const int* __restrict__ col,
                                const float* __restrict__ h, const float* __restrict__ dis,
                                const float* __restrict__ b, float* __restrict__ out, int n,
                                int do_relu) {
    int t = threadIdx.x;
    int node = blockIdx.x * 4 + (t >> 6);
    int lane = t & 63;
    if (node >= n) return;

    int beg = row_ptr[node];
    int end = row_ptr[node + 1];
    float v = h[(size_t)node * NF + lane];  // self-loop

    int j = beg;
    for (; j + 8 <= end; j += 8) {
        int s[8];
#pragma unroll
        for (int q = 0; q < 8; ++q) s[q] = col[j + q];
        float a[8];
#pragma unroll
        for (int q = 0; q < 8; ++q) a[q] = h[(size_t)s[q] * NF + lane];
        float s0 = (a[0] + a[1]) + (a[2] + a[3]);
        float s1 = (a[4] + a[5]) + (a[6] + a[7]);
        v += s0 + s1;
    }
    for (; j < end; ++j) v += h[(size_t)col[j] * NF + lane];

    float r = v * dis[node] + b[lane];
    if (do_relu) r = fmaxf(r, 0.0f);
    out[(size_t)node * NF + lane] = r;
}

// ================= head =================

__global__ void head_kernel(const float* __restrict__ x1, const float* __restrict__ x2,
                            const float* __restrict__ x3, const float* __restrict__ Wl,
                            const float* __restrict__ bl, float* __restrict__ out, int n) {
    __shared__ float Ws[8 * 192];  // Ws[c*192 + j] = Wl[j*8 + c]
    __shared__ float bs[8];
    int t = threadIdx.x;
    for (int idx = t; idx < 8 * 192; idx += 256) {
        int c = idx / 192, j = idx % 192;
        Ws[idx] = Wl[j * 8 + c];
    }
    if (t < 8) bs[t] = bl[t];
    __syncthreads();

    int node = blockIdx.x * 4 + (t >> 6);
    int lane = t & 63;
    if (node >= n) return;

    const float* rows[3] = {x1 + (size_t)node * NF, x2 + (size_t)node * NF,
                            x3 + (size_t)node * NF};
    float acc[8];
#pragma unroll
    for (int c = 0; c < 8; ++c) acc[c] = 0.0f;
#pragma unroll
    for (int p = 0; p < 3; ++p) {
        float v = rows[p][lane];
#pragma unroll
        for (int c = 0; c < 8; ++c) acc[c] += v * Ws[c * 192 + p * 64 + lane];
    }
#pragma unroll
    for (int off = 32; off >= 1; off >>= 1) {
#pragma unroll
        for (int c = 0; c < 8; ++c) acc[c] += __shfl_xor(acc[c], off, 64);
    }
    if (lane < 8) {
        float lg[8];
        float m = -INFINITY;
#pragma unroll
        for (int c = 0; c < 8; ++c) {
            lg[c] = acc[c] + bs[c];
            m = fmaxf(m, lg[c]);
        }
        float s = 0.0f;
#pragma unroll
        for (int c = 0; c < 8; ++c) s += expf(lg[c] - m);
        float lse = m + logf(s);
        out[(size_t)node * 8 + lane] = lg[lane] - lse;
    }
}

// ================= launch =================

extern "C" void kernel_launch(void* const* d_in, const int* in_sizes, int n_in,
                              void* d_out, int out_size, void* d_ws, size_t ws_size,
                              hipStream_t stream) {
    const float* x = (const float*)d_in[0];
    const int* ei = (const int*)d_in[1];  // [2,E]: [0..E)=src, [E..2E)=dst
    const float* W1 = (const float*)d_in[2];
    const float* b1 = (const float*)d_in[3];
    const float* W2 = (const float*)d_in[4];
    const float* b2 = (const float*)d_in[5];
    const float* W3 = (const float*)d_in[6];
    const float* b3 = (const float*)d_in[7];
    const float* Wl = (const float*)d_in[8];
    const float* bl = (const float*)d_in[9];
    float* out = (float*)d_out;

    const int n = in_sizes[0] / 128;  // 50000
    const int e = in_sizes[1] / 2;    // 800000

    // ws layout: dis[n] f32 | row_ptr[n+1] | cursor[n] | bsums[64] | col[e] |
    //            tmp[n*64] f32 | x1 | x2 | x3 (n*64 f32 each)
    float* dis = (float*)d_ws;
    int* row_ptr = (int*)(dis + n);
    int* cursor = row_ptr + (n + 1);
    int* bsums = cursor + n;
    int* col = bsums + 64;
    float* tmp = (float*)(col + e);
    float* x1 = tmp + (size_t)n * NF;
    float* x2 = x1 + (size_t)n * NF;
    float* x3 = x2 + (size_t)n * NF;

    const int B = 256;
    dim3 blk(B);
    dim3 gn((n + B - 1) / B);
    dim3 ge((e + B - 1) / B);
    const int nb = (n + 1023) / 1024;  // scan blocks (49)

    // ---- CSR build (counts live in `cursor`) ----
    zero_int_kernel<<<gn, blk, 0, stream>>>(cursor, n);
    hist_kernel<<<ge, blk, 0, stream>>>(ei + e, cursor, e);
    dis_kernel<<<gn, blk, 0, stream>>>(cursor, dis, n);
    block_scan_kernel<<<dim3(nb), dim3(1024), 0, stream>>>(cursor, row_ptr, bsums, n);
    scan_bsums_kernel<<<dim3(1), dim3(64), 0, stream>>>(bsums, nb);
    add_offsets_kernel<<<gn, blk, 0, stream>>>(row_ptr, bsums, cursor, n, e);
    fill_kernel<<<ge, blk, 0, stream>>>(ei, cursor, col, e);

    dim3 ggemm((n + 63) / 64);  // 64-node tiles
    dim3 gwave((n + 3) / 4);    // wave-per-node kernels

    // ---- layer 1 (K=128, ReLU) ----
    gemm_tile_kernel<128><<<ggemm, blk, 0, stream>>>(x, W1, dis, tmp, n);
    pull_agg_kernel<<<gwave, blk, 0, stream>>>(row_ptr, col, tmp, dis, b1, x1, n, 1);

    // ---- layer 2 (K=64, ReLU) ----
    gemm_tile_kernel<64><<<ggemm, blk, 0, stream>>>(x1, W2, dis, tmp, n);
    pull_agg_kernel<<<gwave, blk, 0, stream>>>(row_ptr, col, tmp, dis, b2, x2, n, 1);

    // ---- layer 3 (K=64, no ReLU) ----
    gemm_tile_kernel<64><<<ggemm, blk, 0, stream>>>(x2, W3, dis, tmp, n);
    pull_agg_kernel<<<gwave, blk, 0, stream>>>(row_ptr, col, tmp, dis, b3, x3, n, 0);

    // ---- head ----
    head_kernel<<<gwave, blk, 0, stream>>>(x1, x2, x3, Wl, bl, out, n);
}

// Round 5
// 323.884 us; speedup vs baseline: 1.8143x; 1.0295x over previous
//
#include <hip/hip_runtime.h>
#include <math.h>

#define NF 64  // feature width of every GCN layer output

// ================= CSR build =================

__global__ void zero_int_kernel(int* __restrict__ p, int n) {
    int i = blockIdx.x * blockDim.x + threadIdx.x;
    if (i < n) p[i] = 0;
}

__global__ void hist_kernel(const int* __restrict__ dst, int* __restrict__ counts, int e) {
    int i = blockIdx.x * blockDim.x + threadIdx.x;
    if (i < e) atomicAdd(&counts[dst[i]], 1);
}

__global__ void dis_kernel(const int* __restrict__ counts, float* __restrict__ dis, int n) {
    int i = blockIdx.x * blockDim.x + threadIdx.x;
    if (i < n) dis[i] = rsqrtf((float)counts[i] + 1.0f);  // +1 = self-loop
}

// per-1024-block exclusive scan of counts -> row_ptr, block totals -> bsums
__global__ void block_scan_kernel(const int* __restrict__ counts, int* __restrict__ row_ptr,
                                  int* __restrict__ bsums, int n) {
    __shared__ int s[1024];
    int t = threadIdx.x;
    int g = blockIdx.x * 1024 + t;
    int v = (g < n) ? counts[g] : 0;
    s[t] = v;
    __syncthreads();
#pragma unroll
    for (int off = 1; off < 1024; off <<= 1) {
        int add = (t >= off) ? s[t - off] : 0;
        __syncthreads();
        s[t] += add;
        __syncthreads();
    }
    if (g < n) row_ptr[g] = s[t] - v;  // exclusive
    if (t == 1023) bsums[blockIdx.x] = s[t];
}

__global__ void scan_bsums_kernel(int* __restrict__ bsums, int nb) {
    int t = threadIdx.x;  // blockDim = 64
    int v = (t < nb) ? bsums[t] : 0;
    int orig = v;
#pragma unroll
    for (int off = 1; off < 64; off <<= 1) {
        int u = __shfl_up(v, off, 64);
        if (t >= off) v += u;
    }
    if (t < nb) bsums[t] = v - orig;  // exclusive
}

__global__ void add_offsets_kernel(int* __restrict__ row_ptr, const int* __restrict__ bsums,
                                   int* __restrict__ cursor, int n, int e) {
    int g = blockIdx.x * blockDim.x + threadIdx.x;
    if (g < n) {
        int r = row_ptr[g] + bsums[g >> 10];
        row_ptr[g] = r;
        cursor[g] = r;
    }
    if (g == 0) row_ptr[n] = e;
}

__global__ void fill_kernel(const int* __restrict__ ei, int* __restrict__ cursor,
                            int* __restrict__ col, int e) {
    int i = blockIdx.x * blockDim.x + threadIdx.x;
    if (i < e) {
        int d = ei[e + i];  // dst
        int j = atomicAdd(&cursor[d], 1);
        col[j] = ei[i];  // src
    }
}

// ================= h' = (X @ W) * dis[row] — register-tiled SGEMM =================
// Block: 64 nodes x 64 feats, 256 threads, each thread 4x4 outputs.
// Inner k-loop unroll CAPPED at 8 (full unroll -> VGPR=256 + scratch spill, r3).

template <int K>
__global__ __launch_bounds__(256) void gemm_tile_kernel(const float* __restrict__ X,
                                                        const float* __restrict__ W,
                                                        const float* __restrict__ dis,
                                                        float* __restrict__ h, int n) {
    __shared__ float Xs[64][68];
    __shared__ float Ws[64][64];
    int t = threadIdx.x;
    int tx = t & 15;  // feat quad index
    int ty = t >> 4;  // node quad index
    int node0 = blockIdx.x * 64;

    float acc[4][4] = {{0.f}};

    for (int kb = 0; kb < K; kb += 64) {
        int i = t >> 2, q = t & 3;
        int nodei = node0 + i;
        if (nodei < n) {
            const float* xr = X + (size_t)nodei * K + kb + q * 16;
#pragma unroll
            for (int f4 = 0; f4 < 4; ++f4) {
                float4 v = *reinterpret_cast<const float4*>(xr + f4 * 4);
                Xs[q * 16 + f4 * 4 + 0][i] = v.x;
                Xs[q * 16 + f4 * 4 + 1][i] = v.y;
                Xs[q * 16 + f4 * 4 + 2][i] = v.z;
                Xs[q * 16 + f4 * 4 + 3][i] = v.w;
            }
        } else {
#pragma unroll
            for (int kk = 0; kk < 16; ++kk) Xs[q * 16 + kk][i] = 0.0f;
        }
        {
            const float* wr = W + (size_t)kb * 64 + t * 16;
            float* wsf = &Ws[0][0] + t * 16;
#pragma unroll
            for (int f4 = 0; f4 < 4; ++f4)
                *reinterpret_cast<float4*>(wsf + f4 * 4) =
                    *reinterpret_cast<const float4*>(wr + f4 * 4);
        }
        __syncthreads();
#pragma unroll 8
        for (int k = 0; k < 64; ++k) {
            float4 xv = *reinterpret_cast<const float4*>(&Xs[k][ty * 4]);
            float4 wv = *reinterpret_cast<const float4*>(&Ws[k][tx * 4]);
            float xa[4] = {xv.x, xv.y, xv.z, xv.w};
            float wa[4] = {wv.x, wv.y, wv.z, wv.w};
#pragma unroll
            for (int m = 0; m < 4; ++m)
#pragma unroll
                for (int f = 0; f < 4; ++f) acc[m][f] += xa[m] * wa[f];
        }
        __syncthreads();
    }

#pragma unroll
    for (int m = 0; m < 4; ++m) {
        int node = node0 + ty * 4 + m;
        if (node < n) {
            float d = dis[node];
            float4 o = make_float4(acc[m][0] * d, acc[m][1] * d, acc[m][2] * d, acc[m][3] * d);
            *reinterpret_cast<float4*>(&h[(size_t)node * NF + tx * 4]) = o;
        }
    }
}

// ================= pull aggregation (fused finalize) =================
// out[v] = relu?( (h'[v] + sum_{s in N(v)} h'[s]) * dis[v] + b )
// One wave per node. Lane = (edge-slot g = lane>>4, feature-quad fq = lane&15):
// each lane loads a float4, so ONE dwordx4 instruction gathers 4 edges (1 KB).
// The 4 lane-groups accumulate disjoint edge subsets; shfl_xor(16,32) merges.

__global__ void pull_agg_kernel(const int* __restrict__ row_ptr, const int* __restrict__ col,
                                const float* __restrict__ h, const float* __restrict__ dis,
                                const float* __restrict__ b, float* __restrict__ out, int n,
                                int do_relu) {
    int t = threadIdx.x;
    int node = blockIdx.x * 4 + (t >> 6);
    int lane = t & 63;
    if (node >= n) return;
    int g = lane >> 4;   // edge sub-slot 0..3
    int fq = lane & 15;  // feature quad 0..15

    int beg = row_ptr[node];
    int end = row_ptr[node + 1];

    float ax = 0.f, ay = 0.f, az = 0.f, aw = 0.f;
    if (g == 0) {  // self-loop counted once
        float4 v = *reinterpret_cast<const float4*>(&h[(size_t)node * NF + fq * 4]);
        ax = v.x; ay = v.y; az = v.z; aw = v.w;
    }

    int j = beg;
    // main: 16 edges per iteration (4 gather instructions in flight)
    for (; j + 16 <= end; j += 16) {
        int c0 = col[j + g];
        int c1 = col[j + 4 + g];
        int c2 = col[j + 8 + g];
        int c3 = col[j + 12 + g];
        float4 v0 = *reinterpret_cast<const float4*>(&h[(size_t)c0 * NF + fq * 4]);
        float4 v1 = *reinterpret_cast<const float4*>(&h[(size_t)c1 * NF + fq * 4]);
        float4 v2 = *reinterpret_cast<const float4*>(&h[(size_t)c2 * NF + fq * 4]);
        float4 v3 = *reinterpret_cast<const float4*>(&h[(size_t)c3 * NF + fq * 4]);
        ax += (v0.x + v1.x) + (v2.x + v3.x);
        ay += (v0.y + v1.y) + (v2.y + v3.y);
        az += (v0.z + v1.z) + (v2.z + v3.z);
        aw += (v0.w + v1.w) + (v2.w + v3.w);
    }
    // tail: 4 edges per iteration, guarded
    for (; j < end; j += 4) {
        int idx = j + g;
        if (idx < end) {
            int c = col[idx];
            float4 v = *reinterpret_cast<const float4*>(&h[(size_t)c * NF + fq * 4]);
            ax += v.x; ay += v.y; az += v.z; aw += v.w;
        }
    }

    // merge the 4 edge-slot groups (lane bits 4 and 5)
    ax += __shfl_xor(ax, 16, 64); ay += __shfl_xor(ay, 16, 64);
    az += __shfl_xor(az, 16, 64); aw += __shfl_xor(aw, 16, 64);
    ax += __shfl_xor(ax, 32, 64); ay += __shfl_xor(ay, 32, 64);
    az += __shfl_xor(az, 32, 64); aw += __shfl_xor(aw, 32, 64);

    if (lane < 16) {
        float d = dis[node];
        float4 bb = *reinterpret_cast<const float4*>(&b[fq * 4]);
        float ox = ax * d + bb.x, oy = ay * d + bb.y;
        float oz = az * d + bb.z, ow = aw * d + bb.w;
        if (do_relu) {
            ox = fmaxf(ox, 0.f); oy = fmaxf(oy, 0.f);
            oz = fmaxf(oz, 0.f); ow = fmaxf(ow, 0.f);
        }
        *reinterpret_cast<float4*>(&out[(size_t)node * NF + fq * 4]) =
            make_float4(ox, oy, oz, ow);
    }
}

// ================= head =================

__global__ void head_kernel(const float* __restrict__ x1, const float* __restrict__ x2,
                            const float* __restrict__ x3, const float* __restrict__ Wl,
                            const float* __restrict__ bl, float* __restrict__ out, int n) {
    __shared__ float Ws[8 * 192];  // Ws[c*192 + j] = Wl[j*8 + c]
    __shared__ float bs[8];
    int t = threadIdx.x;
    for (int idx = t; idx < 8 * 192; idx += 256) {
        int c = idx / 192, j = idx % 192;
        Ws[idx] = Wl[j * 8 + c];
    }
    if (t < 8) bs[t] = bl[t];
    __syncthreads();

    int node = blockIdx.x * 4 + (t >> 6);
    int lane = t & 63;
    if (node >= n) return;

    const float* rows[3] = {x1 + (size_t)node * NF, x2 + (size_t)node * NF,
                            x3 + (size_t)node * NF};
    float acc[8];
#pragma unroll
    for (int c = 0; c < 8; ++c) acc[c] = 0.0f;
#pragma unroll
    for (int p = 0; p < 3; ++p) {
        float v = rows[p][lane];
#pragma unroll
        for (int c = 0; c < 8; ++c) acc[c] += v * Ws[c * 192 + p * 64 + lane];
    }
#pragma unroll
    for (int off = 32; off >= 1; off >>= 1) {
#pragma unroll
        for (int c = 0; c < 8; ++c) acc[c] += __shfl_xor(acc[c], off, 64);
    }
    if (lane < 8) {
        float lg[8];
        float m = -INFINITY;
#pragma unroll
        for (int c = 0; c < 8; ++c) {
            lg[c] = acc[c] + bs[c];
            m = fmaxf(m, lg[c]);
        }
        float s = 0.0f;
#pragma unroll
        for (int c = 0; c < 8; ++c) s += expf(lg[c] - m);
        float lse = m + logf(s);
        out[(size_t)node * 8 + lane] = lg[lane] - lse;
    }
}

// ================= launch =================

extern "C" void kernel_launch(void* const* d_in, const int* in_sizes, int n_in,
                              void* d_out, int out_size, void* d_ws, size_t ws_size,
                              hipStream_t stream) {
    const float* x = (const float*)d_in[0];
    const int* ei = (const int*)d_in[1];  // [2,E]: [0..E)=src, [E..2E)=dst
    const float* W1 = (const float*)d_in[2];
    const float* b1 = (const float*)d_in[3];
    const float* W2 = (const float*)d_in[4];
    const float* b2 = (const float*)d_in[5];
    const float* W3 = (const float*)d_in[6];
    const float* b3 = (const float*)d_in[7];
    const float* Wl = (const float*)d_in[8];
    const float* bl = (const float*)d_in[9];
    float* out = (float*)d_out;

    const int n = in_sizes[0] / 128;  // 50000
    const int e = in_sizes[1] / 2;    // 800000

    // ws layout: dis[n] f32 | row_ptr[n+1] | cursor[n] | bsums[64] | col[e] |
    //            tmp[n*64] f32 | x1 | x2 | x3 (n*64 f32 each)
    float* dis = (float*)d_ws;
    int* row_ptr = (int*)(dis + n);
    int* cursor = row_ptr + (n + 1);
    int* bsums = cursor + n;
    int* col = bsums + 64;
    float* tmp = (float*)(col + e);
    float* x1 = tmp + (size_t)n * NF;
    float* x2 = x1 + (size_t)n * NF;
    float* x3 = x2 + (size_t)n * NF;

    const int B = 256;
    dim3 blk(B);
    dim3 gn((n + B - 1) / B);
    dim3 ge((e + B - 1) / B);
    const int nb = (n + 1023) / 1024;  // scan blocks (49)

    // ---- CSR build (counts live in `cursor`) ----
    zero_int_kernel<<<gn, blk, 0, stream>>>(cursor, n);
    hist_kernel<<<ge, blk, 0, stream>>>(ei + e, cursor, e);
    dis_kernel<<<gn, blk, 0, stream>>>(cursor, dis, n);
    block_scan_kernel<<<dim3(nb), dim3(1024), 0, stream>>>(cursor, row_ptr, bsums, n);
    scan_bsums_kernel<<<dim3(1), dim3(64), 0, stream>>>(bsums, nb);
    add_offsets_kernel<<<gn, blk, 0, stream>>>(row_ptr, bsums, cursor, n, e);
    fill_kernel<<<ge, blk, 0, stream>>>(ei, cursor, col, e);

    dim3 ggemm((n + 63) / 64);  // 64-node tiles
    dim3 gwave((n + 3) / 4);    // wave-per-node kernels

    // ---- layer 1 (K=128, ReLU) ----
    gemm_tile_kernel<128><<<ggemm, blk, 0, stream>>>(x, W1, dis, tmp, n);
    pull_agg_kernel<<<gwave, blk, 0, stream>>>(row_ptr, col, tmp, dis, b1, x1, n, 1);

    // ---- layer 2 (K=64, ReLU) ----
    gemm_tile_kernel<64><<<ggemm, blk, 0, stream>>>(x1, W2, dis, tmp, n);
    pull_agg_kernel<<<gwave, blk, 0, stream>>>(row_ptr, col, tmp, dis, b2, x2, n, 1);

    // ---- layer 3 (K=64, no ReLU) ----
    gemm_tile_kernel<64><<<ggemm, blk, 0, stream>>>(x2, W3, dis, tmp, n);
    pull_agg_kernel<<<gwave, blk, 0, stream>>>(row_ptr, col, tmp, dis, b3, x3, n, 0);

    // ---- head ----
    head_kernel<<<gwave, blk, 0, stream>>>(x1, x2, x3, Wl, bl, out, n);
}

// Round 6
// 255.524 us; speedup vs baseline: 2.2997x; 1.2675x over previous
//
#include <hip/hip_runtime.h>
#include <math.h>

#define NF 64       // feature width of every GCN layer output
#define NB_BITS 7   // 128 nodes per bucket
#define EPW 4096    // edges per partition workgroup

// ================= CSR build v2: bucketed counting sort =================
// Replaces hist/scan/fill (r5: fill alone was 60us with 53MB WRITE_SIZE =
// 16x line amplification from scattered cross-XCD 4B stores). All writes
// here are either coalesced bursts or confined to one WG's small region.
// Pack: (dst<<16)|src in one unsigned (requires n <= 65536; here n=50000).

__global__ void k_zero(int* __restrict__ bucket_counts, int C, int* __restrict__ row_ptr,
                       int n, int e) {
    int i = blockIdx.x * blockDim.x + threadIdx.x;
    if (i < C) bucket_counts[i] = 0;
    if (i == 0) row_ptr[n] = e;
}

__global__ __launch_bounds__(256) void k_bucket_hist(const int* __restrict__ dst, int e,
                                                     int* __restrict__ bucket_counts, int C) {
    __shared__ int h[392];
    int t = threadIdx.x;
    for (int i = t; i < C; i += 256) h[i] = 0;
    __syncthreads();
    int base = blockIdx.x * EPW;
    int lim = min(base + EPW, e);
    for (int i = base + t; i < lim; i += 256) atomicAdd(&h[dst[i] >> NB_BITS], 1);
    __syncthreads();
    for (int i = t; i < C; i += 256)
        if (h[i]) atomicAdd(&bucket_counts[i], h[i]);
}

__global__ __launch_bounds__(512) void k_bucket_scan(const int* __restrict__ counts,
                                                     int* __restrict__ base,
                                                     int* __restrict__ cursor, int C, int e) {
    __shared__ int s[512];
    int t = threadIdx.x;
    int v = (t < C) ? counts[t] : 0;
    s[t] = v;
    __syncthreads();
    for (int off = 1; off < 512; off <<= 1) {
        int add = (t >= off) ? s[t - off] : 0;
        __syncthreads();
        s[t] += add;
        __syncthreads();
    }
    if (t < C) {
        int b = s[t] - v;  // exclusive
        base[t] = b;
        cursor[t] = b;
    }
    if (t == 0) base[C] = e;
}

__global__ __launch_bounds__(256) void k_partition(const int* __restrict__ ei, int e,
                                                   int* __restrict__ cursor,
                                                   unsigned* __restrict__ pairs, int C) {
    __shared__ int hist[392];
    __shared__ int lbase[392];
    __shared__ int gbase[392];
    __shared__ unsigned staged[EPW];
    int t = threadIdx.x;
    for (int i = t; i < C; i += 256) hist[i] = 0;
    __syncthreads();
    int base = blockIdx.x * EPW;
    int lim = min(base + EPW, e) - base;

    // pass A: local bucket histogram
    for (int i = t; i < lim; i += 256) atomicAdd(&hist[ei[e + base + i] >> NB_BITS], 1);
    __syncthreads();

    // wave 0: exclusive scan of hist[0..C) into lbase
    if (t < 64) {
        int carry = 0;
        for (int c = 0; c * 64 < C; ++c) {
            int idx = c * 64 + t;
            int v = (idx < C) ? hist[idx] : 0;
            int x = v;
#pragma unroll
            for (int off = 1; off < 64; off <<= 1) {
                int u = __shfl_up(x, off, 64);
                if (t >= off) x += u;
            }
            if (idx < C) lbase[idx] = x - v + carry;
            carry += __shfl(x, 63, 64);
        }
    }
    __syncthreads();

    // reserve contiguous global runs (one atomic per non-empty bucket)
    for (int i = t; i < C; i += 256) {
        int c = hist[i];
        gbase[i] = c ? atomicAdd(&cursor[i], c) : 0;
    }
    __syncthreads();
    for (int i = t; i < C; i += 256) hist[i] = 0;  // reuse as local cursor
    __syncthreads();

    // pass B: stage pairs grouped by bucket in LDS
    for (int i = t; i < lim; i += 256) {
        int src = ei[base + i];
        int dst = ei[e + base + i];
        int b = dst >> NB_BITS;
        int r = atomicAdd(&hist[b], 1);
        staged[lbase[b] + r] = ((unsigned)dst << 16) | (unsigned)src;
    }
    __syncthreads();

    // flush: contiguous slots -> contiguous run addresses (coalesced)
    for (int s2 = t; s2 < lim; s2 += 256) {
        unsigned p = staged[s2];
        int b = (int)(p >> (16 + NB_BITS));
        pairs[gbase[b] + (s2 - lbase[b])] = p;
    }
}

// one WG per bucket: local node histogram -> dis + row_ptr, then scatter col
// within the bucket's own contiguous region (single-CU, full-line writes).
__global__ __launch_bounds__(256) void k_bucket_build(const unsigned* __restrict__ pairs,
                                                      const int* __restrict__ bbase,
                                                      int* __restrict__ row_ptr,
                                                      float* __restrict__ dis,
                                                      int* __restrict__ col, int n) {
    __shared__ unsigned lp[EPW];
    __shared__ int nh[128], nbase[128], ncur[128];
    int b = blockIdx.x;
    int t = threadIdx.x;
    int beg = bbase[b], end = bbase[b + 1];
    int cnt = end - beg;
    int v0 = b << NB_BITS;
    int nv = min(128, n - v0);
    if (t < 128) {
        nh[t] = 0;
        ncur[t] = 0;
    }
    __syncthreads();
    for (int i = t; i < cnt; i += 256) {
        unsigned p = pairs[beg + i];
        if (i < EPW) lp[i] = p;
        atomicAdd(&nh[(p >> 16) & 127], 1);
    }
    __syncthreads();
    if (t < 64) {  // scan 128 counts (2 chunks) by wave 0
        int carry = 0;
#pragma unroll
        for (int c = 0; c < 2; ++c) {
            int idx = c * 64 + t;
            int v = nh[idx];
            int x = v;
#pragma unroll
            for (int off = 1; off < 64; off <<= 1) {
                int u = __shfl_up(x, off, 64);
                if (t >= off) x += u;
            }
            nbase[idx] = x - v + carry;
            carry += __shfl(x, 63, 64);
        }
    }
    __syncthreads();
    if (t < nv) {
        row_ptr[v0 + t] = beg + nbase[t];
        dis[v0 + t] = rsqrtf((float)nh[t] + 1.0f);
    }
    for (int i = t; i < cnt; i += 256) {
        unsigned p = (i < EPW) ? lp[i] : pairs[beg + i];
        int ld = (p >> 16) & 127;
        int r = atomicAdd(&ncur[ld], 1);
        col[beg + nbase[ld] + r] = (int)(p & 0xFFFFu);
    }
}

// ================= h' = (X @ W) * dis[row] — register-tiled SGEMM =================
// Block: 64 nodes x 64 feats, 256 threads, each thread 4x4 outputs.
// Inner k-loop unroll CAPPED at 8 (full unroll -> VGPR=256 + scratch spill, r3).

template <int K>
__global__ __launch_bounds__(256) void gemm_tile_kernel(const float* __restrict__ X,
                                                        const float* __restrict__ W,
                                                        const float* __restrict__ dis,
                                                        float* __restrict__ h, int n) {
    __shared__ float Xs[64][68];
    __shared__ float Ws[64][64];
    int t = threadIdx.x;
    int tx = t & 15;  // feat quad index
    int ty = t >> 4;  // node quad index
    int node0 = blockIdx.x * 64;

    float acc[4][4] = {{0.f}};

    for (int kb = 0; kb < K; kb += 64) {
        int i = t >> 2, q = t & 3;
        int nodei = node0 + i;
        if (nodei < n) {
            const float* xr = X + (size_t)nodei * K + kb + q * 16;
#pragma unroll
            for (int f4 = 0; f4 < 4; ++f4) {
                float4 v = *reinterpret_cast<const float4*>(xr + f4 * 4);
                Xs[q * 16 + f4 * 4 + 0][i] = v.x;
                Xs[q * 16 + f4 * 4 + 1][i] = v.y;
                Xs[q * 16 + f4 * 4 + 2][i] = v.z;
                Xs[q * 16 + f4 * 4 + 3][i] = v.w;
            }
        } else {
#pragma unroll
            for (int kk = 0; kk < 16; ++kk) Xs[q * 16 + kk][i] = 0.0f;
        }
        {
            const float* wr = W + (size_t)kb * 64 + t * 16;
            float* wsf = &Ws[0][0] + t * 16;
#pragma unroll
            for (int f4 = 0; f4 < 4; ++f4)
                *reinterpret_cast<float4*>(wsf + f4 * 4) =
                    *reinterpret_cast<const float4*>(wr + f4 * 4);
        }
        __syncthreads();
#pragma unroll 8
        for (int k = 0; k < 64; ++k) {
            float4 xv = *reinterpret_cast<const float4*>(&Xs[k][ty * 4]);
            float4 wv = *reinterpret_cast<const float4*>(&Ws[k][tx * 4]);
            float xa[4] = {xv.x, xv.y, xv.z, xv.w};
            float wa[4] = {wv.x, wv.y, wv.z, wv.w};
#pragma unroll
            for (int m = 0; m < 4; ++m)
#pragma unroll
                for (int f = 0; f < 4; ++f) acc[m][f] += xa[m] * wa[f];
        }
        __syncthreads();
    }

#pragma unroll
    for (int m = 0; m < 4; ++m) {
        int node = node0 + ty * 4 + m;
        if (node < n) {
            float d = dis[node];
            float4 o = make_float4(acc[m][0] * d, acc[m][1] * d, acc[m][2] * d, acc[m][3] * d);
            *reinterpret_cast<float4*>(&h[(size_t)node * NF + tx * 4]) = o;
        }
    }
}

// ================= pull aggregation (fused finalize) =================
// out[v] = relu?( (h'[v] + sum_{s in N(v)} h'[s]) * dis[v] + b )
// One wave per node; lane = (edge-slot g = lane>>4, feature-quad fq = lane&15).

__global__ void pull_agg_kernel(const int* __restrict__ row_ptr, const int* __restrict__ col,
                                const float* __restrict__ h, const float* __restrict__ dis,
                                const float* __restrict__ b, float* __restrict__ out, int n,
                                int do_relu) {
    int t = threadIdx.x;
    int node = blockIdx.x * 4 + (t >> 6);
    int lane = t & 63;
    if (node >= n) return;
    int g = lane >> 4;   // edge sub-slot 0..3
    int fq = lane & 15;  // feature quad 0..15

    int beg = row_ptr[node];
    int end = row_ptr[node + 1];

    float ax = 0.f, ay = 0.f, az = 0.f, aw = 0.f;
    if (g == 0) {  // self-loop counted once
        float4 v = *reinterpret_cast<const float4*>(&h[(size_t)node * NF + fq * 4]);
        ax = v.x; ay = v.y; az = v.z; aw = v.w;
    }

    int j = beg;
    for (; j + 16 <= end; j += 16) {
        int c0 = col[j + g];
        int c1 = col[j + 4 + g];
        int c2 = col[j + 8 + g];
        int c3 = col[j + 12 + g];
        float4 v0 = *reinterpret_cast<const float4*>(&h[(size_t)c0 * NF + fq * 4]);
        float4 v1 = *reinterpret_cast<const float4*>(&h[(size_t)c1 * NF + fq * 4]);
        float4 v2 = *reinterpret_cast<const float4*>(&h[(size_t)c2 * NF + fq * 4]);
        float4 v3 = *reinterpret_cast<const float4*>(&h[(size_t)c3 * NF + fq * 4]);
        ax += (v0.x + v1.x) + (v2.x + v3.x);
        ay += (v0.y + v1.y) + (v2.y + v3.y);
        az += (v0.z + v1.z) + (v2.z + v3.z);
        aw += (v0.w + v1.w) + (v2.w + v3.w);
    }
    for (; j < end; j += 4) {
        int idx = j + g;
        if (idx < end) {
            int c = col[idx];
            float4 v = *reinterpret_cast<const float4*>(&h[(size_t)c * NF + fq * 4]);
            ax += v.x; ay += v.y; az += v.z; aw += v.w;
        }
    }

    ax += __shfl_xor(ax, 16, 64); ay += __shfl_xor(ay, 16, 64);
    az += __shfl_xor(az, 16, 64); aw += __shfl_xor(aw, 16, 64);
    ax += __shfl_xor(ax, 32, 64); ay += __shfl_xor(ay, 32, 64);
    az += __shfl_xor(az, 32, 64); aw += __shfl_xor(aw, 32, 64);

    if (lane < 16) {
        float d = dis[node];
        float4 bb = *reinterpret_cast<const float4*>(&b[fq * 4]);
        float ox = ax * d + bb.x, oy = ay * d + bb.y;
        float oz = az * d + bb.z, ow = aw * d + bb.w;
        if (do_relu) {
            ox = fmaxf(ox, 0.f); oy = fmaxf(oy, 0.f);
            oz = fmaxf(oz, 0.f); ow = fmaxf(ow, 0.f);
        }
        *reinterpret_cast<float4*>(&out[(size_t)node * NF + fq * 4]) =
            make_float4(ox, oy, oz, ow);
    }
}

// ================= head =================

__global__ void head_kernel(const float* __restrict__ x1, const float* __restrict__ x2,
                            const float* __restrict__ x3, const float* __restrict__ Wl,
                            const float* __restrict__ bl, float* __restrict__ out, int n) {
    __shared__ float Ws[8 * 192];  // Ws[c*192 + j] = Wl[j*8 + c]
    __shared__ float bs[8];
    int t = threadIdx.x;
    for (int idx = t; idx < 8 * 192; idx += 256) {
        int c = idx / 192, j = idx % 192;
        Ws[idx] = Wl[j * 8 + c];
    }
    if (t < 8) bs[t] = bl[t];
    __syncthreads();

    int node = blockIdx.x * 4 + (t >> 6);
    int lane = t & 63;
    if (node >= n) return;

    const float* rows[3] = {x1 + (size_t)node * NF, x2 + (size_t)node * NF,
                            x3 + (size_t)node * NF};
    float acc[8];
#pragma unroll
    for (int c = 0; c < 8; ++c) acc[c] = 0.0f;
#pragma unroll
    for (int p = 0; p < 3; ++p) {
        float v = rows[p][lane];
#pragma unroll
        for (int c = 0; c < 8; ++c) acc[c] += v * Ws[c * 192 + p * 64 + lane];
    }
#pragma unroll
    for (int off = 32; off >= 1; off >>= 1) {
#pragma unroll
        for (int c = 0; c < 8; ++c) acc[c] += __shfl_xor(acc[c], off, 64);
    }
    if (lane < 8) {
        float lg[8];
        float m = -INFINITY;
#pragma unroll
        for (int c = 0; c < 8; ++c) {
            lg[c] = acc[c] + bs[c];
            m = fmaxf(m, lg[c]);
        }
        float s = 0.0f;
#pragma unroll
        for (int c = 0; c < 8; ++c) s += expf(lg[c] - m);
        float lse = m + logf(s);
        out[(size_t)node * 8 + lane] = lg[lane] - lse;
    }
}

// ================= launch =================

extern "C" void kernel_launch(void* const* d_in, const int* in_sizes, int n_in,
                              void* d_out, int out_size, void* d_ws, size_t ws_size,
                              hipStream_t stream) {
    const float* x = (const float*)d_in[0];
    const int* ei = (const int*)d_in[1];  // [2,E]: [0..E)=src, [E..2E)=dst
    const float* W1 = (const float*)d_in[2];
    const float* b1 = (const float*)d_in[3];
    const float* W2 = (const float*)d_in[4];
    const float* b2 = (const float*)d_in[5];
    const float* W3 = (const float*)d_in[6];
    const float* b3 = (const float*)d_in[7];
    const float* Wl = (const float*)d_in[8];
    const float* bl = (const float*)d_in[9];
    float* out = (float*)d_out;

    const int n = in_sizes[0] / 128;  // 50000
    const int e = in_sizes[1] / 2;    // 800000
    const int C = (n + 127) >> NB_BITS;  // 391 buckets

    // ws layout: dis[n] | row_ptr[n+1] | bbase[C+1] | cursor[C] | bcounts[C] |
    //            col[e] | tmp[n*64] f32 (pairs[e] overlays tmp) | x1 | x2 | x3
    float* dis = (float*)d_ws;
    int* row_ptr = (int*)(dis + n);
    int* bbase = row_ptr + (n + 1);
    int* cursor = bbase + (C + 1);
    int* bcounts = cursor + C;
    int* col = bcounts + C;
    float* tmp = (float*)(col + e);
    unsigned* pairs = (unsigned*)tmp;  // overlay: pairs dead before gemm1 writes tmp
    float* x1 = tmp + (size_t)n * NF;
    float* x2 = x1 + (size_t)n * NF;
    float* x3 = x2 + (size_t)n * NF;

    const int B = 256;
    dim3 blk(B);
    const int PW = (e + EPW - 1) / EPW;  // 196 partition WGs

    // ---- CSR build v2 ----
    k_zero<<<dim3((C + B - 1) / B), blk, 0, stream>>>(bcounts, C, row_ptr, n, e);
    k_bucket_hist<<<dim3(PW), blk, 0, stream>>>(ei + e, e, bcounts, C);
    k_bucket_scan<<<dim3(1), dim3(512), 0, stream>>>(bcounts, bbase, cursor, C, e);
    k_partition<<<dim3(PW), blk, 0, stream>>>(ei, e, cursor, pairs, C);
    k_bucket_build<<<dim3(C), blk, 0, stream>>>(pairs, bbase, row_ptr, dis, col, n);

    dim3 ggemm((n + 63) / 64);  // 64-node tiles
    dim3 gwave((n + 3) / 4);    // wave-per-node kernels

    // ---- layer 1 (K=128, ReLU) ----
    gemm_tile_kernel<128><<<ggemm, blk, 0, stream>>>(x, W1, dis, tmp, n);
    pull_agg_kernel<<<gwave, blk, 0, stream>>>(row_ptr, col, tmp, dis, b1, x1, n, 1);

    // ---- layer 2 (K=64, ReLU) ----
    gemm_tile_kernel<64><<<ggemm, blk, 0, stream>>>(x1, W2, dis, tmp, n);
    pull_agg_kernel<<<gwave, blk, 0, stream>>>(row_ptr, col, tmp, dis, b2, x2, n, 1);

    // ---- layer 3 (K=64, no ReLU) ----
    gemm_tile_kernel<64><<<ggemm, blk, 0, stream>>>(x2, W3, dis, tmp, n);
    pull_agg_kernel<<<gwave, blk, 0, stream>>>(row_ptr, col, tmp, dis, b3, x3, n, 0);

    // ---- head ----
    head_kernel<<<gwave, blk, 0, stream>>>(x1, x2, x3, Wl, bl, out, n);
}

// Round 8
// 184.283 us; speedup vs baseline: 3.1887x; 1.3866x over previous
//
#include <hip/hip_runtime.h>
#include <hip/hip_fp16.h>
#include <math.h>

#define NF 64       // feature width of every GCN layer output
#define NB_BITS 7   // 128 nodes per bucket
#define EPW 4096    // edges per partition workgroup

// ================= CSR build v2: bucketed counting sort =================
// (r6: replaced scattered-atomic hist/fill — 16x write amplification — with
// bucket partition + per-bucket build; all writes coalesced or WG-local.)
// (r8: `pairs` no longer overlays `hh` — cross-call aliasing removed.)

__global__ void k_zero(int* __restrict__ bucket_counts, int C, int* __restrict__ row_ptr,
                       int n, int e) {
    int i = blockIdx.x * blockDim.x + threadIdx.x;
    if (i < C) bucket_counts[i] = 0;
    if (i == 0) row_ptr[n] = e;
}

__global__ __launch_bounds__(256) void k_bucket_hist(const int* __restrict__ dst, int e,
                                                     int* __restrict__ bucket_counts, int C) {
    __shared__ int h[392];
    int t = threadIdx.x;
    for (int i = t; i < C; i += 256) h[i] = 0;
    __syncthreads();
    int base = blockIdx.x * EPW;
    int lim = min(base + EPW, e);
    for (int i = base + t; i < lim; i += 256) atomicAdd(&h[dst[i] >> NB_BITS], 1);
    __syncthreads();
    for (int i = t; i < C; i += 256)
        if (h[i]) atomicAdd(&bucket_counts[i], h[i]);
}

__global__ __launch_bounds__(512) void k_bucket_scan(const int* __restrict__ counts,
                                                     int* __restrict__ base,
                                                     int* __restrict__ cursor, int C, int e) {
    __shared__ int s[512];
    int t = threadIdx.x;
    int v = (t < C) ? counts[t] : 0;
    s[t] = v;
    __syncthreads();
    for (int off = 1; off < 512; off <<= 1) {
        int add = (t >= off) ? s[t - off] : 0;
        __syncthreads();
        s[t] += add;
        __syncthreads();
    }
    if (t < C) {
        int b = s[t] - v;  // exclusive
        base[t] = b;
        cursor[t] = b;
    }
    if (t == 0) base[C] = e;
}

__global__ __launch_bounds__(256) void k_partition(const int* __restrict__ ei, int e,
                                                   int* __restrict__ cursor,
                                                   unsigned* __restrict__ pairs, int C) {
    __shared__ int hist[392];
    __shared__ int lbase[392];
    __shared__ int gbase[392];
    __shared__ unsigned staged[EPW];
    int t = threadIdx.x;
    for (int i = t; i < C; i += 256) hist[i] = 0;
    __syncthreads();
    int base = blockIdx.x * EPW;
    int lim = min(base + EPW, e) - base;

    for (int i = t; i < lim; i += 256) atomicAdd(&hist[ei[e + base + i] >> NB_BITS], 1);
    __syncthreads();

    if (t < 64) {
        int carry = 0;
        for (int c = 0; c * 64 < C; ++c) {
            int idx = c * 64 + t;
            int v = (idx < C) ? hist[idx] : 0;
            int x = v;
#pragma unroll
            for (int off = 1; off < 64; off <<= 1) {
                int u = __shfl_up(x, off, 64);
                if (t >= off) x += u;
            }
            if (idx < C) lbase[idx] = x - v + carry;
            carry += __shfl(x, 63, 64);
        }
    }
    __syncthreads();

    for (int i = t; i < C; i += 256) {
        int c = hist[i];
        gbase[i] = c ? atomicAdd(&cursor[i], c) : 0;
    }
    __syncthreads();
    for (int i = t; i < C; i += 256) hist[i] = 0;
    __syncthreads();

    for (int i = t; i < lim; i += 256) {
        int src = ei[base + i];
        int dst = ei[e + base + i];
        int b = dst >> NB_BITS;
        int r = atomicAdd(&hist[b], 1);
        staged[lbase[b] + r] = ((unsigned)dst << 16) | (unsigned)src;
    }
    __syncthreads();

    for (int s2 = t; s2 < lim; s2 += 256) {
        unsigned p = staged[s2];
        int b = (int)(p >> (16 + NB_BITS));
        pairs[gbase[b] + (s2 - lbase[b])] = p;
    }
}

__global__ __launch_bounds__(256) void k_bucket_build(const unsigned* __restrict__ pairs,
                                                      const int* __restrict__ bbase,
                                                      int* __restrict__ row_ptr,
                                                      float* __restrict__ dis,
                                                      int* __restrict__ col, int n) {
    __shared__ unsigned lp[EPW];
    __shared__ int nh[128], nbase[128], ncur[128];
    int b = blockIdx.x;
    int t = threadIdx.x;
    int beg = bbase[b], end = bbase[b + 1];
    int cnt = end - beg;
    int v0 = b << NB_BITS;
    int nv = min(128, n - v0);
    if (t < 128) {
        nh[t] = 0;
        ncur[t] = 0;
    }
    __syncthreads();
    for (int i = t; i < cnt; i += 256) {
        unsigned p = pairs[beg + i];
        if (i < EPW) lp[i] = p;
        atomicAdd(&nh[(p >> 16) & 127], 1);
    }
    __syncthreads();
    if (t < 64) {
        int carry = 0;
#pragma unroll
        for (int c = 0; c < 2; ++c) {
            int idx = c * 64 + t;
            int v = nh[idx];
            int x = v;
#pragma unroll
            for (int off = 1; off < 64; off <<= 1) {
                int u = __shfl_up(x, off, 64);
                if (t >= off) x += u;
            }
            nbase[idx] = x - v + carry;
            carry += __shfl(x, 63, 64);
        }
    }
    __syncthreads();
    if (t < nv) {
        row_ptr[v0 + t] = beg + nbase[t];
        dis[v0 + t] = rsqrtf((float)nh[t] + 1.0f);
    }
    for (int i = t; i < cnt; i += 256) {
        unsigned p = (i < EPW) ? lp[i] : pairs[beg + i];
        int ld = (p >> 16) & 127;
        int r = atomicAdd(&ncur[ld], 1);
        col[beg + nbase[ld] + r] = (int)(p & 0xFFFFu);
    }
}

// ================= h' = (X @ W) * dis[row] — register-tiled SGEMM, fp16 out =====
// Block: 64 nodes x 64 feats, 256 threads, each thread 4x4 outputs.
// Inner k-loop unroll CAPPED at 8 (full unroll -> VGPR=256 + scratch spill, r3).

template <int K>
__global__ __launch_bounds__(256) void gemm_tile_kernel(const float* __restrict__ X,
                                                        const float* __restrict__ W,
                                                        const float* __restrict__ dis,
                                                        __half* __restrict__ h, int n) {
    __shared__ float Xs[64][68];
    __shared__ float Ws[64][64];
    int t = threadIdx.x;
    int tx = t & 15;  // feat quad index
    int ty = t >> 4;  // node quad index
    int node0 = blockIdx.x * 64;

    float acc[4][4] = {{0.f}};

    for (int kb = 0; kb < K; kb += 64) {
        int i = t >> 2, q = t & 3;
        int nodei = node0 + i;
        if (nodei < n) {
            const float* xr = X + (size_t)nodei * K + kb + q * 16;
#pragma unroll
            for (int f4 = 0; f4 < 4; ++f4) {
                float4 v = *reinterpret_cast<const float4*>(xr + f4 * 4);
                Xs[q * 16 + f4 * 4 + 0][i] = v.x;
                Xs[q * 16 + f4 * 4 + 1][i] = v.y;
                Xs[q * 16 + f4 * 4 + 2][i] = v.z;
                Xs[q * 16 + f4 * 4 + 3][i] = v.w;
            }
        } else {
#pragma unroll
            for (int kk = 0; kk < 16; ++kk) Xs[q * 16 + kk][i] = 0.0f;
        }
        {
            const float* wr = W + (size_t)kb * 64 + t * 16;
            float* wsf = &Ws[0][0] + t * 16;
#pragma unroll
            for (int f4 = 0; f4 < 4; ++f4)
                *reinterpret_cast<float4*>(wsf + f4 * 4) =
                    *reinterpret_cast<const float4*>(wr + f4 * 4);
        }
        __syncthreads();
#pragma unroll 8
        for (int k = 0; k < 64; ++k) {
            float4 xv = *reinterpret_cast<const float4*>(&Xs[k][ty * 4]);
            float4 wv = *reinterpret_cast<const float4*>(&Ws[k][tx * 4]);
            float xa[4] = {xv.x, xv.y, xv.z, xv.w};
            float wa[4] = {wv.x, wv.y, wv.z, wv.w};
#pragma unroll
            for (int m = 0; m < 4; ++m)
#pragma unroll
                for (int f = 0; f < 4; ++f) acc[m][f] += xa[m] * wa[f];
        }
        __syncthreads();
    }

#pragma unroll
    for (int m = 0; m < 4; ++m) {
        int node = node0 + ty * 4 + m;
        if (node < n) {
            float d = dis[node];
            __half2 p0 = __floats2half2_rn(acc[m][0] * d, acc[m][1] * d);
            __half2 p1 = __floats2half2_rn(acc[m][2] * d, acc[m][3] * d);
            unsigned u0 = *reinterpret_cast<unsigned*>(&p0);
            unsigned u1 = *reinterpret_cast<unsigned*>(&p1);
            *reinterpret_cast<uint2*>(&h[(size_t)node * NF + tx * 4]) = make_uint2(u0, u1);
        }
    }
}

// ================= pull aggregation (fused finalize), fp16 gather =================
// One wave per node; lane = (edge-slot g = lane>>3, feature-oct fo = lane&7):
// each lane loads 16B = 8 halves; 32 edges in flight per main iteration.
// fp32 accumulate, butterfly(8,16,32) merges the 8 edge-slot groups.

__device__ inline void acc_add8(float acc[8], float4 raw) {
    const __half2* hp = reinterpret_cast<const __half2*>(&raw);
#pragma unroll
    for (int q = 0; q < 4; ++q) {
        float2 f = __half22float2(hp[q]);
        acc[2 * q] += f.x;
        acc[2 * q + 1] += f.y;
    }
}

__global__ void pull_agg_kernel(const int* __restrict__ row_ptr, const int* __restrict__ col,
                                const __half* __restrict__ h, const float* __restrict__ dis,
                                const float* __restrict__ b, float* __restrict__ out, int n,
                                int do_relu) {
    int t = threadIdx.x;
    int node = blockIdx.x * 4 + (t >> 6);
    int lane = t & 63;
    if (node >= n) return;
    int g = lane >> 3;  // edge sub-slot 0..7
    int fo = lane & 7;  // feature oct 0..7

    int beg = row_ptr[node];
    int end = row_ptr[node + 1];

    float acc[8] = {0.f, 0.f, 0.f, 0.f, 0.f, 0.f, 0.f, 0.f};
    if (g == 0) {  // self-loop counted once
        float4 raw = *reinterpret_cast<const float4*>(&h[(size_t)node * NF + fo * 8]);
        acc_add8(acc, raw);
    }

    int j = beg;
    for (; j + 32 <= end; j += 32) {
        int c0 = col[j + g];
        int c1 = col[j + 8 + g];
        int c2 = col[j + 16 + g];
        int c3 = col[j + 24 + g];
        float4 r0 = *reinterpret_cast<const float4*>(&h[(size_t)c0 * NF + fo * 8]);
        float4 r1 = *reinterpret_cast<const float4*>(&h[(size_t)c1 * NF + fo * 8]);
        float4 r2 = *reinterpret_cast<const float4*>(&h[(size_t)c2 * NF + fo * 8]);
        float4 r3 = *reinterpret_cast<const float4*>(&h[(size_t)c3 * NF + fo * 8]);
        acc_add8(acc, r0);
        acc_add8(acc, r1);
        acc_add8(acc, r2);
        acc_add8(acc, r3);
    }
    for (; j < end; j += 8) {
        int idx = j + g;
        if (idx < end) {
            int c = col[idx];
            float4 r = *reinterpret_cast<const float4*>(&h[(size_t)c * NF + fo * 8]);
            acc_add8(acc, r);
        }
    }

#pragma unroll
    for (int off = 8; off <= 32; off <<= 1)
#pragma unroll
        for (int k = 0; k < 8; ++k) acc[k] += __shfl_xor(acc[k], off, 64);

    if (g == 0) {
        float d = dis[node];
        float4 b0 = *reinterpret_cast<const float4*>(&b[fo * 8]);
        float4 b1 = *reinterpret_cast<const float4*>(&b[fo * 8 + 4]);
        float o0 = acc[0] * d + b0.x, o1 = acc[1] * d + b0.y;
        float o2 = acc[2] * d + b0.z, o3 = acc[3] * d + b0.w;
        float o4 = acc[4] * d + b1.x, o5 = acc[5] * d + b1.y;
        float o6 = acc[6] * d + b1.z, o7 = acc[7] * d + b1.w;
        if (do_relu) {
            o0 = fmaxf(o0, 0.f); o1 = fmaxf(o1, 0.f); o2 = fmaxf(o2, 0.f);
            o3 = fmaxf(o3, 0.f); o4 = fmaxf(o4, 0.f); o5 = fmaxf(o5, 0.f);
            o6 = fmaxf(o6, 0.f); o7 = fmaxf(o7, 0.f);
        }
        float* op = &out[(size_t)node * NF + fo * 8];
        *reinterpret_cast<float4*>(op) = make_float4(o0, o1, o2, o3);
        *reinterpret_cast<float4*>(op + 4) = make_float4(o4, o5, o6, o7);
    }
}

// ================= head: 8 nodes per wave =================

__global__ __launch_bounds__(256) void head_kernel(const float* __restrict__ x1,
                                                   const float* __restrict__ x2,
                                                   const float* __restrict__ x3,
                                                   const float* __restrict__ Wl,
                                                   const float* __restrict__ bl,
                                                   float* __restrict__ out, int n) {
    __shared__ float ws[8 * 192];  // ws[k*192 + f] = Wl[f*8 + k]
    __shared__ float bs[8];
    int t = threadIdx.x;
    for (int idx = t; idx < 8 * 192; idx += 256) {
        int k = idx / 192, f = idx % 192;
        ws[idx] = Wl[f * 8 + k];
    }
    if (t < 8) bs[t] = bl[t];
    __syncthreads();

    int wave = t >> 6, lane = t & 63;
    int ns = lane >> 3, c = lane & 7;
    int node = blockIdx.x * 32 + wave * 8 + ns;
    if (node >= n) return;

    float acc[8] = {0.f, 0.f, 0.f, 0.f, 0.f, 0.f, 0.f, 0.f};
#pragma unroll
    for (int chunk = 0; chunk < 6; ++chunk) {
        const float* base = (chunk < 2) ? x1 : ((chunk < 4) ? x2 : x3);
        float4 xv = *reinterpret_cast<const float4*>(
            &base[(size_t)node * NF + (chunk & 1) * 32 + c * 4]);
#pragma unroll
        for (int k = 0; k < 8; ++k) {
            float4 wv = *reinterpret_cast<const float4*>(&ws[k * 192 + chunk * 32 + c * 4]);
            acc[k] += xv.x * wv.x + xv.y * wv.y + xv.z * wv.z + xv.w * wv.w;
        }
    }
#pragma unroll
    for (int off = 1; off <= 4; off <<= 1)
#pragma unroll
        for (int k = 0; k < 8; ++k) acc[k] += __shfl_xor(acc[k], off, 64);

    float lg[8];
    float m = -INFINITY;
#pragma unroll
    for (int k = 0; k < 8; ++k) {
        lg[k] = acc[k] + bs[k];
        m = fmaxf(m, lg[k]);
    }
    float s = 0.f;
#pragma unroll
    for (int k = 0; k < 8; ++k) s += expf(lg[k] - m);
    float lse = m + logf(s);
    out[(size_t)node * 8 + c] = lg[c] - lse;
}

// ================= launch =================

extern "C" void kernel_launch(void* const* d_in, const int* in_sizes, int n_in,
                              void* d_out, int out_size, void* d_ws, size_t ws_size,
                              hipStream_t stream) {
    const float* x = (const float*)d_in[0];
    const int* ei = (const int*)d_in[1];  // [2,E]: [0..E)=src, [E..2E)=dst
    const float* W1 = (const float*)d_in[2];
    const float* b1 = (const float*)d_in[3];
    const float* W2 = (const float*)d_in[4];
    const float* b2 = (const float*)d_in[5];
    const float* W3 = (const float*)d_in[6];
    const float* b3 = (const float*)d_in[7];
    const float* Wl = (const float*)d_in[8];
    const float* bl = (const float*)d_in[9];
    float* out = (float*)d_out;

    const int n = in_sizes[0] / 128;     // 50000
    const int e = in_sizes[1] / 2;       // 800000
    const int C = (n + 127) >> NB_BITS;  // 391 buckets

    // ws layout (all offsets padded to 64B so fp16/float4 regions are 16B-aligned):
    // dis[n] | row_ptr[n+1] | bbase[C+1] | cursor[C] | bcounts[C] | col[e] |
    // tmp region [n*64 floats]: hh fp16 in lower half, pairs in UPPER half
    // (disjoint — r7's hh/pairs overlay caused post-timing divergence) | x1|x2|x3
    auto pad16 = [](size_t v) { return (v + 15) & ~(size_t)15; };
    float* wsf = (float*)d_ws;
    size_t o = 0;
    float* dis = wsf + o;      o += pad16(n);
    int* row_ptr = (int*)(wsf + o); o += pad16(n + 1);
    int* bbase = (int*)(wsf + o);   o += pad16(C + 1);
    int* cursor = (int*)(wsf + o);  o += pad16(C);
    int* bcounts = (int*)(wsf + o); o += pad16(C);
    int* col = (int*)(wsf + o);     o += pad16(e);
    float* tmp = wsf + o;           o += (size_t)n * NF;  // n*64 floats, 16B-aligned
    __half* hh = (__half*)tmp;                        // n*64 halfs = lower half
    unsigned* pairs = (unsigned*)(tmp + (size_t)n * (NF / 2));  // upper half, disjoint
    float* x1 = wsf + o;            o += (size_t)n * NF;
    float* x2 = wsf + o;            o += (size_t)n * NF;
    float* x3 = wsf + o;            o += (size_t)n * NF;

    const int B = 256;
    dim3 blk(B);
    const int PW = (e + EPW - 1) / EPW;

    // ---- CSR build v2 ----
    k_zero<<<dim3((C + B - 1) / B), blk, 0, stream>>>(bcounts, C, row_ptr, n, e);
    k_bucket_hist<<<dim3(PW), blk, 0, stream>>>(ei + e, e, bcounts, C);
    k_bucket_scan<<<dim3(1), dim3(512), 0, stream>>>(bcounts, bbase, cursor, C, e);
    k_partition<<<dim3(PW), blk, 0, stream>>>(ei, e, cursor, pairs, C);
    k_bucket_build<<<dim3(C), blk, 0, stream>>>(pairs, bbase, row_ptr, dis, col, n);

    dim3 ggemm((n + 63) / 64);
    dim3 gwave((n + 3) / 4);
    dim3 ghead((n + 31) / 32);

    // ---- layer 1 (K=128, ReLU) ----
    gemm_tile_kernel<128><<<ggemm, blk, 0, stream>>>(x, W1, dis, hh, n);
    pull_agg_kernel<<<gwave, blk, 0, stream>>>(row_ptr, col, hh, dis, b1, x1, n, 1);

    // ---- layer 2 (K=64, ReLU) ----
    gemm_tile_kernel<64><<<ggemm, blk, 0, stream>>>(x1, W2, dis, hh, n);
    pull_agg_kernel<<<gwave, blk, 0, stream>>>(row_ptr, col, hh, dis, b2, x2, n, 1);

    // ---- layer 3 (K=64, no ReLU) ----
    gemm_tile_kernel<64><<<ggemm, blk, 0, stream>>>(x2, W3, dis, hh, n);
    pull_agg_kernel<<<gwave, blk, 0, stream>>>(row_ptr, col, hh, dis, b3, x3, n, 0);

    // ---- head ----
    head_kernel<<<ghead, blk, 0, stream>>>(x1, x2, x3, Wl, bl, out, n);
}

// Round 9
// 164.584 us; speedup vs baseline: 3.5704x; 1.1197x over previous
//
#include <hip/hip_runtime.h>
#include <hip/hip_fp16.h>
#include <math.h>

#define NF 64       // feature width of every GCN layer output
#define NB_BITS 7   // 128 nodes per bucket
#define EPW 4096    // edges per partition workgroup

typedef _Float16 f16x8 __attribute__((ext_vector_type(8)));
typedef float f32x4 __attribute__((ext_vector_type(4)));

// ================= CSR build v2: bucketed counting sort =================
// (r6: replaced scattered-atomic hist/fill — 16x write amplification — with
// bucket partition + per-bucket build; all writes coalesced or WG-local.)
// (r8: `pairs` fully disjoint from all other regions — no cross-call aliasing.)

__global__ void k_zero(int* __restrict__ bucket_counts, int C, int* __restrict__ row_ptr,
                       int n, int e) {
    int i = blockIdx.x * blockDim.x + threadIdx.x;
    if (i < C) bucket_counts[i] = 0;
    if (i == 0) row_ptr[n] = e;
}

__global__ __launch_bounds__(256) void k_bucket_hist(const int* __restrict__ dst, int e,
                                                     int* __restrict__ bucket_counts, int C) {
    __shared__ int h[392];
    int t = threadIdx.x;
    for (int i = t; i < C; i += 256) h[i] = 0;
    __syncthreads();
    int base = blockIdx.x * EPW;
    int lim = min(base + EPW, e);
    for (int i = base + t; i < lim; i += 256) atomicAdd(&h[dst[i] >> NB_BITS], 1);
    __syncthreads();
    for (int i = t; i < C; i += 256)
        if (h[i]) atomicAdd(&bucket_counts[i], h[i]);
}

__global__ __launch_bounds__(512) void k_bucket_scan(const int* __restrict__ counts,
                                                     int* __restrict__ base,
                                                     int* __restrict__ cursor, int C, int e) {
    __shared__ int s[512];
    int t = threadIdx.x;
    int v = (t < C) ? counts[t] : 0;
    s[t] = v;
    __syncthreads();
    for (int off = 1; off < 512; off <<= 1) {
        int add = (t >= off) ? s[t - off] : 0;
        __syncthreads();
        s[t] += add;
        __syncthreads();
    }
    if (t < C) {
        int b = s[t] - v;  // exclusive
        base[t] = b;
        cursor[t] = b;
    }
    if (t == 0) base[C] = e;
}

__global__ __launch_bounds__(256) void k_partition(const int* __restrict__ ei, int e,
                                                   int* __restrict__ cursor,
                                                   unsigned* __restrict__ pairs, int C) {
    __shared__ int hist[392];
    __shared__ int lbase[392];
    __shared__ int gbase[392];
    __shared__ unsigned staged[EPW];
    int t = threadIdx.x;
    for (int i = t; i < C; i += 256) hist[i] = 0;
    __syncthreads();
    int base = blockIdx.x * EPW;
    int lim = min(base + EPW, e) - base;

    for (int i = t; i < lim; i += 256) atomicAdd(&hist[ei[e + base + i] >> NB_BITS], 1);
    __syncthreads();

    if (t < 64) {
        int carry = 0;
        for (int c = 0; c * 64 < C; ++c) {
            int idx = c * 64 + t;
            int v = (idx < C) ? hist[idx] : 0;
            int x = v;
#pragma unroll
            for (int off = 1; off < 64; off <<= 1) {
                int u = __shfl_up(x, off, 64);
                if (t >= off) x += u;
            }
            if (idx < C) lbase[idx] = x - v + carry;
            carry += __shfl(x, 63, 64);
        }
    }
    __syncthreads();

    for (int i = t; i < C; i += 256) {
        int c = hist[i];
        gbase[i] = c ? atomicAdd(&cursor[i], c) : 0;
    }
    __syncthreads();
    for (int i = t; i < C; i += 256) hist[i] = 0;
    __syncthreads();

    for (int i = t; i < lim; i += 256) {
        int src = ei[base + i];
        int dst = ei[e + base + i];
        int b = dst >> NB_BITS;
        int r = atomicAdd(&hist[b], 1);
        staged[lbase[b] + r] = ((unsigned)dst << 16) | (unsigned)src;
    }
    __syncthreads();

    for (int s2 = t; s2 < lim; s2 += 256) {
        unsigned p = staged[s2];
        int b = (int)(p >> (16 + NB_BITS));
        pairs[gbase[b] + (s2 - lbase[b])] = p;
    }
}

__global__ __launch_bounds__(256) void k_bucket_build(const unsigned* __restrict__ pairs,
                                                      const int* __restrict__ bbase,
                                                      int* __restrict__ row_ptr,
                                                      float* __restrict__ dis,
                                                      int* __restrict__ col, int n) {
    __shared__ unsigned lp[EPW];
    __shared__ int nh[128], nbase[128], ncur[128];
    int b = blockIdx.x;
    int t = threadIdx.x;
    int beg = bbase[b], end = bbase[b + 1];
    int cnt = end - beg;
    int v0 = b << NB_BITS;
    int nv = min(128, n - v0);
    if (t < 128) {
        nh[t] = 0;
        ncur[t] = 0;
    }
    __syncthreads();
    for (int i = t; i < cnt; i += 256) {
        unsigned p = pairs[beg + i];
        if (i < EPW) lp[i] = p;
        atomicAdd(&nh[(p >> 16) & 127], 1);
    }
    __syncthreads();
    if (t < 64) {
        int carry = 0;
#pragma unroll
        for (int c = 0; c < 2; ++c) {
            int idx = c * 64 + t;
            int v = nh[idx];
            int x = v;
#pragma unroll
            for (int off = 1; off < 64; off <<= 1) {
                int u = __shfl_up(x, off, 64);
                if (t >= off) x += u;
            }
            nbase[idx] = x - v + carry;
            carry += __shfl(x, 63, 64);
        }
    }
    __syncthreads();
    if (t < nv) {
        row_ptr[v0 + t] = beg + nbase[t];
        dis[v0 + t] = rsqrtf((float)nh[t] + 1.0f);
    }
    for (int i = t; i < cnt; i += 256) {
        unsigned p = (i < EPW) ? lp[i] : pairs[beg + i];
        int ld = (p >> 16) & 127;
        int r = atomicAdd(&ncur[ld], 1);
        col[beg + nbase[ld] + r] = (int)(p & 0xFFFFu);
    }
}

// ================= X fp32 -> fp16 =================

__global__ __launch_bounds__(256) void x_to_half_kernel(const float* __restrict__ X,
                                                        __half* __restrict__ Xh, size_t total) {
    size_t i = ((size_t)blockIdx.x * 256 + threadIdx.x) * 8;
    if (i >= total) return;
    float4 a = *reinterpret_cast<const float4*>(X + i);
    float4 b = *reinterpret_cast<const float4*>(X + i + 4);
    __half2 p0 = __floats2half2_rn(a.x, a.y);
    __half2 p1 = __floats2half2_rn(a.z, a.w);
    __half2 p2 = __floats2half2_rn(b.x, b.y);
    __half2 p3 = __floats2half2_rn(b.z, b.w);
    uint4 u = make_uint4(*reinterpret_cast<unsigned*>(&p0), *reinterpret_cast<unsigned*>(&p1),
                         *reinterpret_cast<unsigned*>(&p2), *reinterpret_cast<unsigned*>(&p3));
    *reinterpret_cast<uint4*>(&Xh[i]) = u;
}

// ================= h' = (X @ W) * dis[row] — MFMA f16 GEMM =================
// 256 thr = 4 waves; block tile 64 nodes x 64 f. Wave w: nodes [w*16,w*16+16).
// mfma_f32_16x16x32_f16: A-frag lane = X[node0+w*16+(l&15)][k0+8*(l>>4)+j]
// (16B contiguous global); B-frag lane = W^T[f=l&15][same k] from LDS-transposed
// W (row stride K+8 halves -> 2-way bank alias = free). D: col=l&15=f,
// row=4*(l>>4)+reg (m89-verified). fp32 accumulate; dis-scale + fp16 store.

template <int K>
__global__ __launch_bounds__(256) void gemm_mfma_kernel(const __half* __restrict__ Xh,
                                                        const float* __restrict__ W,
                                                        const float* __restrict__ dis,
                                                        __half* __restrict__ h, int n) {
    __shared__ _Float16 Wt[64][K + 8];
    int t = threadIdx.x;
    for (int idx = t; idx < 64 * K; idx += 256) {
        int k = idx >> 6, f = idx & 63;
        Wt[f][k] = (_Float16)W[idx];
    }
    __syncthreads();

    int wave = t >> 6, l = t & 63;
    int lr = l & 15;  // A: node row in tile / B: f col in tile
    int lg = l >> 4;  // k-group (8 halves each)
    int node0 = blockIdx.x * 64 + wave * 16;

    int arow = node0 + lr;
    const __half* xrow = Xh + (size_t)min(arow, n - 1) * K;

    f32x4 acc[4];
#pragma unroll
    for (int ft = 0; ft < 4; ++ft) acc[ft] = (f32x4){0.f, 0.f, 0.f, 0.f};

#pragma unroll
    for (int k0 = 0; k0 < K; k0 += 32) {
        f16x8 a = *reinterpret_cast<const f16x8*>(xrow + k0 + lg * 8);
#pragma unroll
        for (int ft = 0; ft < 4; ++ft) {
            f16x8 b = *reinterpret_cast<const f16x8*>(&Wt[ft * 16 + lr][k0 + lg * 8]);
            acc[ft] = __builtin_amdgcn_mfma_f32_16x16x32_f16(a, b, acc[ft], 0, 0, 0);
        }
    }

    int rbase = node0 + 4 * lg;
#pragma unroll
    for (int r = 0; r < 4; ++r) {
        int node = rbase + r;
        if (node < n) {
            float d = dis[node];
#pragma unroll
            for (int ft = 0; ft < 4; ++ft)
                h[(size_t)node * NF + ft * 16 + lr] = __float2half(acc[ft][r] * d);
        }
    }
}

// ================= pull aggregation (fused finalize), fp16 in/out =================
// One wave per node; lane = (edge-slot g = lane>>3, feature-oct fo = lane&7):
// each lane loads 16B = 8 halves; 32 edges in flight per main iteration.
// fp32 accumulate, butterfly(8,16,32) merges the 8 edge-slot groups.

__device__ inline void acc_add8(float acc[8], float4 raw) {
    const __half2* hp = reinterpret_cast<const __half2*>(&raw);
#pragma unroll
    for (int q = 0; q < 4; ++q) {
        float2 f = __half22float2(hp[q]);
        acc[2 * q] += f.x;
        acc[2 * q + 1] += f.y;
    }
}

__global__ void pull_agg_kernel(const int* __restrict__ row_ptr, const int* __restrict__ col,
                                const __half* __restrict__ h, const float* __restrict__ dis,
                                const float* __restrict__ b, __half* __restrict__ out, int n,
                                int do_relu) {
    int t = threadIdx.x;
    int node = blockIdx.x * 4 + (t >> 6);
    int lane = t & 63;
    if (node >= n) return;
    int g = lane >> 3;  // edge sub-slot 0..7
    int fo = lane & 7;  // feature oct 0..7

    int beg = row_ptr[node];
    int end = row_ptr[node + 1];

    float acc[8] = {0.f, 0.f, 0.f, 0.f, 0.f, 0.f, 0.f, 0.f};
    if (g == 0) {  // self-loop counted once
        float4 raw = *reinterpret_cast<const float4*>(&h[(size_t)node * NF + fo * 8]);
        acc_add8(acc, raw);
    }

    int j = beg;
    for (; j + 32 <= end; j += 32) {
        int c0 = col[j + g];
        int c1 = col[j + 8 + g];
        int c2 = col[j + 16 + g];
        int c3 = col[j + 24 + g];
        float4 r0 = *reinterpret_cast<const float4*>(&h[(size_t)c0 * NF + fo * 8]);
        float4 r1 = *reinterpret_cast<const float4*>(&h[(size_t)c1 * NF + fo * 8]);
        float4 r2 = *reinterpret_cast<const float4*>(&h[(size_t)c2 * NF + fo * 8]);
        float4 r3 = *reinterpret_cast<const float4*>(&h[(size_t)c3 * NF + fo * 8]);
        acc_add8(acc, r0);
        acc_add8(acc, r1);
        acc_add8(acc, r2);
        acc_add8(acc, r3);
    }
    for (; j < end; j += 8) {
        int idx = j + g;
        if (idx < end) {
            int c = col[idx];
            float4 r = *reinterpret_cast<const float4*>(&h[(size_t)c * NF + fo * 8]);
            acc_add8(acc, r);
        }
    }

#pragma unroll
    for (int off = 8; off <= 32; off <<= 1)
#pragma unroll
        for (int k = 0; k < 8; ++k) acc[k] += __shfl_xor(acc[k], off, 64);

    if (g == 0) {
        float d = dis[node];
        float4 b0 = *reinterpret_cast<const float4*>(&b[fo * 8]);
        float4 b1 = *reinterpret_cast<const float4*>(&b[fo * 8 + 4]);
        float o0 = acc[0] * d + b0.x, o1 = acc[1] * d + b0.y;
        float o2 = acc[2] * d + b0.z, o3 = acc[3] * d + b0.w;
        float o4 = acc[4] * d + b1.x, o5 = acc[5] * d + b1.y;
        float o6 = acc[6] * d + b1.z, o7 = acc[7] * d + b1.w;
        if (do_relu) {
            o0 = fmaxf(o0, 0.f); o1 = fmaxf(o1, 0.f); o2 = fmaxf(o2, 0.f);
            o3 = fmaxf(o3, 0.f); o4 = fmaxf(o4, 0.f); o5 = fmaxf(o5, 0.f);
            o6 = fmaxf(o6, 0.f); o7 = fmaxf(o7, 0.f);
        }
        __half2 p0 = __floats2half2_rn(o0, o1);
        __half2 p1 = __floats2half2_rn(o2, o3);
        __half2 p2 = __floats2half2_rn(o4, o5);
        __half2 p3 = __floats2half2_rn(o6, o7);
        uint4 u = make_uint4(*reinterpret_cast<unsigned*>(&p0), *reinterpret_cast<unsigned*>(&p1),
                             *reinterpret_cast<unsigned*>(&p2), *reinterpret_cast<unsigned*>(&p3));
        *reinterpret_cast<uint4*>(&out[(size_t)node * NF + fo * 8]) = u;
    }
}

// ================= head: 8 nodes per wave, fp16 inputs =================

__global__ __launch_bounds__(256) void head_kernel(const __half* __restrict__ x1,
                                                   const __half* __restrict__ x2,
                                                   const __half* __restrict__ x3,
                                                   const float* __restrict__ Wl,
                                                   const float* __restrict__ bl,
                                                   float* __restrict__ out, int n) {
    __shared__ float ws[8 * 192];  // ws[k*192 + f] = Wl[f*8 + k]
    __shared__ float bs[8];
    int t = threadIdx.x;
    for (int idx = t; idx < 8 * 192; idx += 256) {
        int k = idx / 192, f = idx % 192;
        ws[idx] = Wl[f * 8 + k];
    }
    if (t < 8) bs[t] = bl[t];
    __syncthreads();

    int wave = t >> 6, lane = t & 63;
    int ns = lane >> 3, c = lane & 7;
    int node = blockIdx.x * 32 + wave * 8 + ns;
    if (node >= n) return;

    float acc[8] = {0.f, 0.f, 0.f, 0.f, 0.f, 0.f, 0.f, 0.f};
#pragma unroll
    for (int chunk = 0; chunk < 6; ++chunk) {
        const __half* base = (chunk < 2) ? x1 : ((chunk < 4) ? x2 : x3);
        uint2 raw = *reinterpret_cast<const uint2*>(
            &base[(size_t)node * NF + (chunk & 1) * 32 + c * 4]);
        const __half2* hp = reinterpret_cast<const __half2*>(&raw);
        float2 f0 = __half22float2(hp[0]);
        float2 f1 = __half22float2(hp[1]);
#pragma unroll
        for (int k = 0; k < 8; ++k) {
            float4 wv = *reinterpret_cast<const float4*>(&ws[k * 192 + chunk * 32 + c * 4]);
            acc[k] += f0.x * wv.x + f0.y * wv.y + f1.x * wv.z + f1.y * wv.w;
        }
    }
#pragma unroll
    for (int off = 1; off <= 4; off <<= 1)
#pragma unroll
        for (int k = 0; k < 8; ++k) acc[k] += __shfl_xor(acc[k], off, 64);

    float lg[8];
    float m = -INFINITY;
#pragma unroll
    for (int k = 0; k < 8; ++k) {
        lg[k] = acc[k] + bs[k];
        m = fmaxf(m, lg[k]);
    }
    float s = 0.f;
#pragma unroll
    for (int k = 0; k < 8; ++k) s += expf(lg[k] - m);
    float lse = m + logf(s);
    out[(size_t)node * 8 + c] = lg[c] - lse;
}

// ================= launch =================

extern "C" void kernel_launch(void* const* d_in, const int* in_sizes, int n_in,
                              void* d_out, int out_size, void* d_ws, size_t ws_size,
                              hipStream_t stream) {
    const float* x = (const float*)d_in[0];
    const int* ei = (const int*)d_in[1];  // [2,E]: [0..E)=src, [E..2E)=dst
    const float* W1 = (const float*)d_in[2];
    const float* b1 = (const float*)d_in[3];
    const float* W2 = (const float*)d_in[4];
    const float* b2 = (const float*)d_in[5];
    const float* W3 = (const float*)d_in[6];
    const float* b3 = (const float*)d_in[7];
    const float* Wl = (const float*)d_in[8];
    const float* bl = (const float*)d_in[9];
    float* out = (float*)d_out;

    const int n = in_sizes[0] / 128;     // 50000
    const int e = in_sizes[1] / 2;       // 800000
    const int C = (n + 127) >> NB_BITS;  // 391 buckets

    // ws layout (float units, 64B-padded; ALL regions disjoint — no overlays):
    auto pad16 = [](size_t v) { return (v + 15) & ~(size_t)15; };
    float* wsf = (float*)d_ws;
    size_t o = 0;
    float* dis = wsf + o;           o += pad16(n);
    int* row_ptr = (int*)(wsf + o); o += pad16(n + 1);
    int* bbase = (int*)(wsf + o);   o += pad16(C + 1);
    int* cursor = (int*)(wsf + o);  o += pad16(C);
    int* bcounts = (int*)(wsf + o); o += pad16(C);
    int* col = (int*)(wsf + o);     o += pad16(e);
    unsigned* pairs = (unsigned*)(wsf + o); o += pad16(e);
    __half* hh = (__half*)(wsf + o);  o += (size_t)n * (NF / 2);   // n*64 halves
    __half* Xh = (__half*)(wsf + o);  o += (size_t)n * 64;         // n*128 halves
    __half* x1h = (__half*)(wsf + o); o += (size_t)n * (NF / 2);
    __half* x2h = (__half*)(wsf + o); o += (size_t)n * (NF / 2);
    __half* x3h = (__half*)(wsf + o); o += (size_t)n * (NF / 2);

    const int B = 256;
    dim3 blk(B);
    const int PW = (e + EPW - 1) / EPW;

    // ---- X -> fp16 (independent; run first) ----
    size_t xtotal = (size_t)n * 128;
    x_to_half_kernel<<<dim3((xtotal / 8 + B - 1) / B), blk, 0, stream>>>(x, Xh, xtotal);

    // ---- CSR build v2 ----
    k_zero<<<dim3((C + B - 1) / B), blk, 0, stream>>>(bcounts, C, row_ptr, n, e);
    k_bucket_hist<<<dim3(PW), blk, 0, stream>>>(ei + e, e, bcounts, C);
    k_bucket_scan<<<dim3(1), dim3(512), 0, stream>>>(bcounts, bbase, cursor, C, e);
    k_partition<<<dim3(PW), blk, 0, stream>>>(ei, e, cursor, pairs, C);
    k_bucket_build<<<dim3(C), blk, 0, stream>>>(pairs, bbase, row_ptr, dis, col, n);

    dim3 ggemm((n + 63) / 64);
    dim3 gwave((n + 3) / 4);
    dim3 ghead((n + 31) / 32);

    // ---- layer 1 (K=128, ReLU) ----
    gemm_mfma_kernel<128><<<ggemm, blk, 0, stream>>>(Xh, W1, dis, hh, n);
    pull_agg_kernel<<<gwave, blk, 0, stream>>>(row_ptr, col, hh, dis, b1, x1h, n, 1);

    // ---- layer 2 (K=64, ReLU) ----
    gemm_mfma_kernel<64><<<ggemm, blk, 0, stream>>>(x1h, W2, dis, hh, n);
    pull_agg_kernel<<<gwave, blk, 0, stream>>>(row_ptr, col, hh, dis, b2, x2h, n, 1);

    // ---- layer 3 (K=64, no ReLU) ----
    gemm_mfma_kernel<64><<<ggemm, blk, 0, stream>>>(x2h, W3, dis, hh, n);
    pull_agg_kernel<<<gwave, blk, 0, stream>>>(row_ptr, col, hh, dis, b3, x3h, n, 0);

    // ---- head ----
    head_kernel<<<ghead, blk, 0, stream>>>(x1h, x2h, x3h, Wl, bl, out, n);
}